// Round 6
// baseline (3630.319 us; speedup 1.0000x reference)
//
#include <hip/hip_runtime.h>

// Problem constants: T=128, B=64, D=1024, H=1024. fp32 throughout (the
// recurrence is chaotic: per-step gate noise amplifies ~1e3x over 128 steps;
// fp32 order-noise lands at ~4e-3 absmax, bf16 would fail the 2e-2 gate).
#define TT 128
#define BB 64
#define DD 1024
#define HH 1024
#define G4 4096          // 4*H
#define MM (TT*BB)       // 8192 rows of X flattened
#define BH (BB*HH)       // 65536, one timestep of h/out

#define NWG 256          // persistent grid: 1 block per CU (r0 partition —
                         // r1/r3 proved co-resident same-domain blocks
                         // phase-lock and contend without overlap)
#define RPAD 520         // red row pad: 520%32==8 -> reader gather 2-way (free)

typedef float f32x4 __attribute__((ext_vector_type(4)));

__device__ __forceinline__ float hsig(float x) {
    x += 0.5f;
    return fminf(fmaxf(x, 0.0f), 1.0f);
}
__device__ __forceinline__ float htanh(float x) {
    return fminf(fmaxf(x, -1.0f), 1.0f);
}

// ---------------------------------------------------------------------------
__global__ void zero_bar(unsigned* p) {
    p[threadIdx.x] = 0u;   // flags[256]
}

// ---------------------------------------------------------------------------
// Gx[8192][4096] = X[8192][1024] @ Wx[1024][4096] + bias  (proven, ~500 us =
// ~87% of fp32 vector peak — leave alone unless switching to bf16x3 MFMA)
__global__ __launch_bounds__(256) void gx_gemm(const float* __restrict__ X,
                                               const float* __restrict__ W,
                                               const float* __restrict__ bias,
                                               float* __restrict__ C) {
    __shared__ float As[16][132];
    __shared__ float Bs[16][132];

    const int tid = threadIdx.x;
    const int tx = tid & 15;
    const int ty = tid >> 4;
    const int m0 = blockIdx.y * 128;
    const int n0 = blockIdx.x * 128;

    float acc[8][8] = {};
    float4 ra[2], rb[2];

    #pragma unroll
    for (int i = 0; i < 2; ++i) {
        int f4 = tid + i * 256;
        ra[i] = *(const float4*)(X + (size_t)(m0 + (f4 >> 2)) * DD + (f4 & 3) * 4);
        rb[i] = *(const float4*)(W + (size_t)(f4 >> 5) * G4 + n0 + (f4 & 31) * 4);
    }

    for (int k0 = 0; k0 < DD; k0 += 16) {
        #pragma unroll
        for (int i = 0; i < 2; ++i) {
            int f4 = tid + i * 256;
            int mi = f4 >> 2, kq = f4 & 3;
            As[kq * 4 + 0][mi] = ra[i].x;
            As[kq * 4 + 1][mi] = ra[i].y;
            As[kq * 4 + 2][mi] = ra[i].z;
            As[kq * 4 + 3][mi] = ra[i].w;
            *(float4*)&Bs[f4 >> 5][(f4 & 31) * 4] = rb[i];
        }
        __syncthreads();

        const int kn = (k0 + 16 < DD) ? (k0 + 16) : k0;
        #pragma unroll
        for (int i = 0; i < 2; ++i) {
            int f4 = tid + i * 256;
            ra[i] = *(const float4*)(X + (size_t)(m0 + (f4 >> 2)) * DD + kn + (f4 & 3) * 4);
            rb[i] = *(const float4*)(W + (size_t)(kn + (f4 >> 5)) * G4 + n0 + (f4 & 31) * 4);
        }

        #pragma unroll
        for (int kk = 0; kk < 16; ++kk) {
            float ar[8], br[8];
            *(float4*)&ar[0] = *(const float4*)&As[kk][ty * 4];
            *(float4*)&ar[4] = *(const float4*)&As[kk][64 + ty * 4];
            *(float4*)&br[0] = *(const float4*)&Bs[kk][tx * 4];
            *(float4*)&br[4] = *(const float4*)&Bs[kk][64 + tx * 4];
            #pragma unroll
            for (int i = 0; i < 8; ++i)
                #pragma unroll
                for (int j = 0; j < 8; ++j)
                    acc[i][j] += ar[i] * br[j];
        }
        __syncthreads();
    }

    float bl[8];
    *(float4*)&bl[0] = *(const float4*)(bias + n0 + tx * 4);
    *(float4*)&bl[4] = *(const float4*)(bias + n0 + 64 + tx * 4);
    #pragma unroll
    for (int i = 0; i < 8; ++i) {
        int mrow = m0 + ty * 4 + (i & 3) + 64 * (i >> 2);
        float* crow = C + (size_t)mrow * G4 + n0;
        float4 o1, o2;
        o1.x = acc[i][0] + bl[0]; o1.y = acc[i][1] + bl[1];
        o1.z = acc[i][2] + bl[2]; o1.w = acc[i][3] + bl[3];
        o2.x = acc[i][4] + bl[4]; o2.y = acc[i][5] + bl[5];
        o2.z = acc[i][6] + bl[6]; o2.w = acc[i][7] + bl[7];
        *(float4*)(crow + tx * 4) = o1;
        *(float4*)(crow + 64 + tx * 4) = o2;
    }
}

// ---------------------------------------------------------------------------
// Register-stream helpers for the recurrent matmul (static indices only).
#define LOADW(BUF, K4)                                                    \
    {   const float* wn_ = wbase + (size_t)(K4) * 4 * G4;                 \
        _Pragma("unroll")                                                 \
        for (int j_ = 0; j_ < 4; ++j_) {                                  \
            BUF[j_*2]   = *(const f32x4*)(wn_ + (size_t)j_ * G4);         \
            BUF[j_*2+1] = *(const f32x4*)(wn_ + (size_t)j_ * G4 + 4);     \
        } }

#define LOADH(BUF, K4)                                                    \
    {   _Pragma("unroll")                                                 \
        for (int b_ = 0; b_ < 8; ++b_)                                    \
            BUF[b_] = *(const f32x4*)&hs[b_ * 1152 + kc * 36 + (K4) * 4]; }

#define FMA8(WB, HB)                                                      \
    {   _Pragma("unroll")                                                 \
        for (int j_ = 0; j_ < 4; ++j_) {                                  \
            _Pragma("unroll")                                             \
            for (int b_ = 0; b_ < 8; ++b_) {                              \
                float h_ = HB[b_][j_];                                    \
                acc[b_][0] += h_ * WB[j_*2][0];                           \
                acc[b_][1] += h_ * WB[j_*2][1];                           \
                acc[b_][2] += h_ * WB[j_*2][2];                           \
                acc[b_][3] += h_ * WB[j_*2][3];                           \
                acc[b_][4] += h_ * WB[j_*2+1][0];                         \
                acc[b_][5] += h_ * WB[j_*2+1][1];                         \
                acc[b_][6] += h_ * WB[j_*2+1][2];                         \
                acc[b_][7] += h_ * WB[j_*2+1][3];                         \
            } } }

// ---------------------------------------------------------------------------
// Persistent recurrence — r5 pipeline structure with the VGPR cap lifted.
//
// VGPR-CAP LADDER measured on this toolchain (__launch_bounds__ 2nd arg is
// min BLOCKS/CU): (512,4)->cap 64 (r1 spill disaster); (512,2)->cap 128;
// single-arg default->cap 128 (r5: demand ~220 -> SPILLED, WRITE_SIZE
// 34MB->1.46GB, persist 2950us); (512,1)->cap 256. Grid is 1 block/CU by
// design, so declaring min-1-block costs nothing: 8 waves/CU either way.
//
// Pipeline fixes under test (r4 diagnosed the FMA phase as L2-latency-
// stalled at 2 waves/SIMD: VALUBusy 36%, step 14.9us vs ~9us pipe-sum):
//  (1) REGISTER DOUBLE-BUFFERING of Wh (L2) + hv (LDS) streams: wb[2][8] +
//      hv[2][8] f32x4 prefetch k4+1 while k4's 256 FMAs issue.
//  (2) GROUP-LOCAL stage->FMA: thread group kc==p consumes ONLY producer
//      p's h chunk — the same 16 threads that stage it. One wave = one PC:
//      ds_write then s_waitcnt lgkmcnt(0) makes sibling-lane writes visible
//      with NO __syncthreads. Each wave polls only its 4 producers.
//  (3) MERGED one-pass reduction (two red regions, LDS 137 KB, fine at 1
//      block/CU): 6 barriers/step -> 4.
// FENCE-FREE cross-wg h exchange: agent-scope relaxed stores + sc0
// (L2-cached, L1-bypassed) loads. Consumer-L2 lines for out[t-1] are always
// cold before the flag-gated read, so L2 caching is safe and same-btile
// blocks on an XCD share staged lines (r0: 206 MB FETCH; r2's sc1 bypass
// cost 2.44 GB). Ordering: h stores -> vmcnt(0) -> barrier -> flag store.
__global__ __launch_bounds__(512, 1) void lstm_persist(const float* __restrict__ Gx,
                                                       const float* __restrict__ Wh,
                                                       float* __restrict__ out,
                                                       unsigned* __restrict__ flags) {
    // layout (floats): red0 [32][520] = 16640 (hs[8][1152]=9216 aliases its
    // head) | red1 [32][520] = 16640 | gsum 1024.  Total 34304 fl = 137.2 KB.
    __shared__ float smem[2 * 16640 + 1024];
    float* hs   = smem;
    float* red0 = smem;
    float* red1 = smem + 16640;
    float* gsum = smem + 2 * 16640;

    const int tid   = threadIdx.x;
    const int btile = blockIdx.x >> 5;     // 0..7
    const int hct   = blockIdx.x & 31;     // 0..31
    const int b0  = btile * 8;
    const int hc0 = hct * 32;

    // matmul identity: kc = 32-k chunk (0..31), tt = 8 gate-cols (0..15)
    const int kc = tid >> 4;
    const int tt = tid & 15;
    const int gate_m = tt >> 2;            // 0..3
    const int sub8 = (tt & 3) * 8;         // 0,8,16,24 within the 32-col block
    const float* wbase = Wh + (size_t)(kc * 32) * G4 + gate_m * HH + hc0 + sub8;

    // staging identity: 16 threads per producer (same 16 that FMA chunk pp)
    const int pp  = kc;                    // producer 0..31 == own k-chunk
    const int srow = tt >> 1;              // 0..7 local b row
    const int cq0  = (tt & 1) * 4;         // first of 4 consecutive f32x4 slots

    // cell identity (tid<256): one (b, hcol) cell per thread, c in creg
    const bool cell_act = (tid < 256);
    const int cb  = tid >> 5;              // 0..7 local b (tid<256)
    const int chc = tid & 31;              // 0..31 local h col
    const size_t cell_g = (size_t)(b0 + cb) * G4 + hc0 + chc;
    const size_t cell_h = (size_t)(b0 + cb) * HH + hc0 + chc;
    float creg = 0.0f;

    // reduction reader identity: 512 readers, two (b, gate-col) sums each
    const int rb_ = tid >> 7;              // 0..3
    const int rgc = tid & 127;             // gate-col 0..127 (= tt*8 + j)
    const int rtt = rgc >> 3;              // writer tt
    const int rj  = rgc & 7;               // writer j

    unsigned* gflags = flags + btile * 32; // this btile group's 32 flags

    // ---- t = 0: gates = Gx[0] (h0 = c0 = 0); publish h(0) through IC
    if (cell_act) {
        const float* gr = Gx + cell_g;
        float ii = hsig(gr[0]);
        float gv = htanh(gr[2 * HH]);
        float oo = hsig(gr[3 * HH]);
        creg = ii * gv;
        __hip_atomic_store(out + cell_h, oo * htanh(creg),
                           __ATOMIC_RELAXED, __HIP_MEMORY_SCOPE_AGENT);
    }
    asm volatile("s_waitcnt vmcnt(0)" ::: "memory");
    __syncthreads();
    if (tid == 0)
        __hip_atomic_store(gflags + hct, 1u, __ATOMIC_RELAXED,
                           __HIP_MEMORY_SCOPE_AGENT);

    for (int t = 1; t < TT; ++t) {
        // prefetch this step's Gx gate values (own data; overlaps the wait)
        float gi = 0.f, gf = 0.f, gg = 0.f, go = 0.f;
        if (cell_act) {
            const float* gr = Gx + (size_t)t * BB * G4 + cell_g;
            gi = gr[0];
            gf = gr[HH];
            gg = gr[2 * HH];
            go = gr[3 * HH];
        }

        float acc[8][8] = {};
        f32x4 wb0[8], wb1[8], hv0[8], hv1[8];

        // w is h-independent: issue k4=0's Wh loads BEFORE the flag poll —
        // full L2 latency hides under poll+stage.
        LOADW(wb0, 0);

        // ---- group-local: poll OWN producer's flag (4 producers per wave)
        while (__hip_atomic_load(gflags + pp, __ATOMIC_RELAXED,
                                 __HIP_MEMORY_SCOPE_AGENT) < (unsigned)t)
            __builtin_amdgcn_s_sleep(1);

        // ---- stage own 64B slice of chunk pp (4 x 16B sc0, L2-cached)
        {
            const float* hp = out + (size_t)(t - 1) * BH
                            + (size_t)(b0 + srow) * HH + pp * 32 + cq0 * 4;
            f32x4 v0, v1, v2, v3;
            asm volatile(
                "global_load_dwordx4 %0, %4, off sc0\n\t"
                "global_load_dwordx4 %1, %4, off offset:16 sc0\n\t"
                "global_load_dwordx4 %2, %4, off offset:32 sc0\n\t"
                "global_load_dwordx4 %3, %4, off offset:48 sc0\n\t"
                "s_waitcnt vmcnt(0)"
                : "=&v"(v0), "=&v"(v1), "=&v"(v2), "=&v"(v3)
                : "v"(hp)
                : "memory");
            float* hd = &hs[srow * 1152 + pp * 36 + cq0 * 4];
            *(f32x4*)(hd)      = v0;
            *(f32x4*)(hd + 4)  = v1;
            *(f32x4*)(hd + 8)  = v2;
            *(f32x4*)(hd + 12) = v3;
        }
        // wave-internal visibility: one PC per wave -> all 64 lanes' ds_write
        // retired after lgkmcnt(0). No block barrier needed (group p reads
        // ONLY chunk p, which group p itself staged).
        asm volatile("s_waitcnt lgkmcnt(0)" ::: "memory");
        __builtin_amdgcn_sched_barrier(0);

        // ---- FMA: acc[8 b][8 gc] over k in [kc*32, kc*32+32), double-
        // buffered register streams for both Wh (L2) and hv (LDS).
        LOADH(hv0, 0);
        #pragma unroll 1
        for (int kk = 0; kk < 4; ++kk) {
            LOADW(wb1, kk * 2 + 1);
            LOADH(hv1, kk * 2 + 1);
            FMA8(wb0, hv0);
            if (kk < 3) {
                LOADW(wb0, kk * 2 + 2);
                LOADH(hv0, kk * 2 + 2);
            }
            FMA8(wb1, hv1);
        }
        __syncthreads();                   // F: hs dead; smem becomes red

        // ---- merged one-pass reduce: write all 64 partials (both halves),
        // one barrier, gather both. write red[vidx][tid]: consecutive-tid,
        // conflict-free. read stride 16, RPAD%32==8 -> 2-way = free.
        #pragma unroll
        for (int bi = 0; bi < 4; ++bi)
            #pragma unroll
            for (int j = 0; j < 8; ++j) {
                red0[(size_t)(bi * 8 + j) * RPAD + tid] = acc[bi][j];
                red1[(size_t)(bi * 8 + j) * RPAD + tid] = acc[4 + bi][j];
            }
        __syncthreads();                   // W
        {
            const float* rp0 = red0 + (size_t)(rb_ * 8 + rj) * RPAD + rtt;
            const float* rp1 = red1 + (size_t)(rb_ * 8 + rj) * RPAD + rtt;
            float a0 = 0.f, a1 = 0.f, a2 = 0.f, a3 = 0.f;
            float c0 = 0.f, c1 = 0.f, c2 = 0.f, c3 = 0.f;
            #pragma unroll
            for (int k2 = 0; k2 < 32; k2 += 4) {
                a0 += rp0[(k2 + 0) * 16];
                a1 += rp0[(k2 + 1) * 16];
                a2 += rp0[(k2 + 2) * 16];
                a3 += rp0[(k2 + 3) * 16];
                c0 += rp1[(k2 + 0) * 16];
                c1 += rp1[(k2 + 1) * 16];
                c2 += rp1[(k2 + 2) * 16];
                c3 += rp1[(k2 + 3) * 16];
            }
            gsum[rb_ * 128 + rgc]       = (a0 + a1) + (a2 + a3);
            gsum[(4 + rb_) * 128 + rgc] = (c0 + c1) + (c2 + c3);
        }
        __syncthreads();                   // G

        // ---- cell update (thread-local c); publish h through IC
        if (cell_act) {
            float ii = hsig(gi + gsum[cb * 128 + chc]);
            float ff = hsig(gf + gsum[cb * 128 + 32 + chc]);
            float gv = htanh(gg + gsum[cb * 128 + 64 + chc]);
            float oo = hsig(go + gsum[cb * 128 + 96 + chc]);
            creg = ff * creg + ii * gv;
            __hip_atomic_store(out + (size_t)t * BH + cell_h, oo * htanh(creg),
                               __ATOMIC_RELAXED, __HIP_MEMORY_SCOPE_AGENT);
        }
        asm volatile("s_waitcnt vmcnt(0)" ::: "memory");
        __syncthreads();                   // P
        if (tid == 0)
            __hip_atomic_store(gflags + hct, (unsigned)(t + 1),
                               __ATOMIC_RELAXED, __HIP_MEMORY_SCOPE_AGENT);
    }
}

// ---------------------------------------------------------------------------
extern "C" void kernel_launch(void* const* d_in, const int* in_sizes, int n_in,
                              void* d_out, int out_size, void* d_ws, size_t ws_size,
                              hipStream_t stream) {
    const float* x  = (const float*)d_in[0];   // [T,B,D]
    const float* Wx = (const float*)d_in[1];   // [D,4H]
    const float* Wh = (const float*)d_in[2];   // [H,4H]
    const float* bs = (const float*)d_in[3];   // [4H]
    float* out = (float*)d_out;                // [T,B,H] — doubles as h history

    // ws layout (floats): Gx 33,554,432 | flags (256 u32)
    float* Gx = (float*)d_ws;
    unsigned* flags = (unsigned*)(Gx + (size_t)MM * G4);

    zero_bar<<<dim3(1), dim3(256), 0, stream>>>(flags);

    // Gx = X @ Wx + b for all timesteps at once
    gx_gemm<<<dim3(G4 / 128, MM / 128), dim3(256), 0, stream>>>(x, Wx, bs, Gx);

    // all 128 recurrent steps in one plain-launch persistent kernel
    lstm_persist<<<dim3(NWG), dim3(512), 0, stream>>>(Gx, Wh, out, flags);
}

// Round 7
// 3485.738 us; speedup vs baseline: 1.0415x; 1.0415x over previous
//
#include <hip/hip_runtime.h>

// Problem constants: T=128, B=64, D=1024, H=1024. fp32 throughout (the
// recurrence is chaotic: per-step gate noise amplifies ~1e3x over 128 steps;
// fp32 order-noise lands at ~4e-3 absmax, bf16 would fail the 2e-2 gate).
#define TT 128
#define BB 64
#define DD 1024
#define HH 1024
#define G4 4096          // 4*H
#define MM (TT*BB)       // 8192 rows of X flattened
#define BH (BB*HH)       // 65536, one timestep of h/out

#define NWG 256          // persistent grid: 1 block per CU (r0 partition —
                         // r1/r3 proved co-resident same-domain blocks
                         // phase-lock and contend without overlap)
#define RPAD 520         // red row pad: 520%32==8 -> reader gather 2-way (free)

typedef float f32x4 __attribute__((ext_vector_type(4)));

__device__ __forceinline__ float hsig(float x) {
    x += 0.5f;
    return fminf(fmaxf(x, 0.0f), 1.0f);
}
__device__ __forceinline__ float htanh(float x) {
    return fminf(fmaxf(x, -1.0f), 1.0f);
}

// ---------------------------------------------------------------------------
__global__ void zero_bar(unsigned* p) {
    p[threadIdx.x] = 0u;   // flags[256]
}

// ---------------------------------------------------------------------------
// Gx[8192][4096] = X[8192][1024] @ Wx[1024][4096] + bias  (proven, ~500 us =
// ~87% of fp32 vector peak — leave alone unless switching to bf16x3 MFMA)
__global__ __launch_bounds__(256) void gx_gemm(const float* __restrict__ X,
                                               const float* __restrict__ W,
                                               const float* __restrict__ bias,
                                               float* __restrict__ C) {
    __shared__ float As[16][132];
    __shared__ float Bs[16][132];

    const int tid = threadIdx.x;
    const int tx = tid & 15;
    const int ty = tid >> 4;
    const int m0 = blockIdx.y * 128;
    const int n0 = blockIdx.x * 128;

    float acc[8][8] = {};
    float4 ra[2], rb[2];

    #pragma unroll
    for (int i = 0; i < 2; ++i) {
        int f4 = tid + i * 256;
        ra[i] = *(const float4*)(X + (size_t)(m0 + (f4 >> 2)) * DD + (f4 & 3) * 4);
        rb[i] = *(const float4*)(W + (size_t)(f4 >> 5) * G4 + n0 + (f4 & 31) * 4);
    }

    for (int k0 = 0; k0 < DD; k0 += 16) {
        #pragma unroll
        for (int i = 0; i < 2; ++i) {
            int f4 = tid + i * 256;
            int mi = f4 >> 2, kq = f4 & 3;
            As[kq * 4 + 0][mi] = ra[i].x;
            As[kq * 4 + 1][mi] = ra[i].y;
            As[kq * 4 + 2][mi] = ra[i].z;
            As[kq * 4 + 3][mi] = ra[i].w;
            *(float4*)&Bs[f4 >> 5][(f4 & 31) * 4] = rb[i];
        }
        __syncthreads();

        const int kn = (k0 + 16 < DD) ? (k0 + 16) : k0;
        #pragma unroll
        for (int i = 0; i < 2; ++i) {
            int f4 = tid + i * 256;
            ra[i] = *(const float4*)(X + (size_t)(m0 + (f4 >> 2)) * DD + kn + (f4 & 3) * 4);
            rb[i] = *(const float4*)(W + (size_t)(kn + (f4 >> 5)) * G4 + n0 + (f4 & 31) * 4);
        }

        #pragma unroll
        for (int kk = 0; kk < 16; ++kk) {
            float ar[8], br[8];
            *(float4*)&ar[0] = *(const float4*)&As[kk][ty * 4];
            *(float4*)&ar[4] = *(const float4*)&As[kk][64 + ty * 4];
            *(float4*)&br[0] = *(const float4*)&Bs[kk][tx * 4];
            *(float4*)&br[4] = *(const float4*)&Bs[kk][64 + tx * 4];
            #pragma unroll
            for (int i = 0; i < 8; ++i)
                #pragma unroll
                for (int j = 0; j < 8; ++j)
                    acc[i][j] += ar[i] * br[j];
        }
        __syncthreads();
    }

    float bl[8];
    *(float4*)&bl[0] = *(const float4*)(bias + n0 + tx * 4);
    *(float4*)&bl[4] = *(const float4*)(bias + n0 + 64 + tx * 4);
    #pragma unroll
    for (int i = 0; i < 8; ++i) {
        int mrow = m0 + ty * 4 + (i & 3) + 64 * (i >> 2);
        float* crow = C + (size_t)mrow * G4 + n0;
        float4 o1, o2;
        o1.x = acc[i][0] + bl[0]; o1.y = acc[i][1] + bl[1];
        o1.z = acc[i][2] + bl[2]; o1.w = acc[i][3] + bl[3];
        o2.x = acc[i][4] + bl[4]; o2.y = acc[i][5] + bl[5];
        o2.z = acc[i][6] + bl[6]; o2.w = acc[i][7] + bl[7];
        *(float4*)(crow + tx * 4) = o1;
        *(float4*)(crow + 64 + tx * 4) = o2;
    }
}

// ---------------------------------------------------------------------------
// Register-stream helpers for the recurrent matmul (static indices only).
#define LOADW(BUF, K4)                                                    \
    {   const float* wn_ = wbase + (size_t)(K4) * 4 * G4;                 \
        _Pragma("unroll")                                                 \
        for (int j_ = 0; j_ < 4; ++j_) {                                  \
            BUF[j_*2]   = *(const f32x4*)(wn_ + (size_t)j_ * G4);         \
            BUF[j_*2+1] = *(const f32x4*)(wn_ + (size_t)j_ * G4 + 4);     \
        } }

#define LOADH(BUF, K4)                                                    \
    {   _Pragma("unroll")                                                 \
        for (int b_ = 0; b_ < 8; ++b_)                                    \
            BUF[b_] = *(const f32x4*)&hs[b_ * 1152 + kc * 36 + (K4) * 4]; }

#define FMA8(WB, HB)                                                      \
    {   _Pragma("unroll")                                                 \
        for (int j_ = 0; j_ < 4; ++j_) {                                  \
            _Pragma("unroll")                                             \
            for (int b_ = 0; b_ < 8; ++b_) {                              \
                float h_ = HB[b_][j_];                                    \
                acc[b_][0] += h_ * WB[j_*2][0];                           \
                acc[b_][1] += h_ * WB[j_*2][1];                           \
                acc[b_][2] += h_ * WB[j_*2][2];                           \
                acc[b_][3] += h_ * WB[j_*2][3];                           \
                acc[b_][4] += h_ * WB[j_*2+1][0];                         \
                acc[b_][5] += h_ * WB[j_*2+1][1];                         \
                acc[b_][6] += h_ * WB[j_*2+1][2];                         \
                acc[b_][7] += h_ * WB[j_*2+1][3];                         \
            } } }

// ---------------------------------------------------------------------------
// Persistent recurrence — r5/r6 pipeline structure; third attempt at lifting
// the VGPR cap, this time with the allocator's actual knob.
//
// VGPR-CAP LADDER measured (rounds 1-6): __launch_bounds__ 2nd arg can only
// LOWER the budget below the default 4-waves/EU target: (512,4)->64,
// (512,2)->128, default->128, (512,1)->128 (r6: does NOT raise). The
// allocator divides the 512-reg/lane/SIMD pool by its waves/EU target
// (measured halving: 8w@64, 4w@128, 2w@256). amdgpu_waves_per_eu(2) sets
// that target to 2 -> budget 256. Our kernel IS 2 waves/EU structurally
// (1 block x 8 waves / 4 SIMDs; LDS 137 KB forces 1 block/CU), so min=2
// gives up nothing. Demand ~230 fits. TRIPWIRE: if VGPR_Count is still 128,
// the attribute is inert on this toolchain -> abandon register pipelining.
//
// Pipeline fixes under test (r4 diagnosed the FMA phase as L2-latency-
// stalled at 2 waves/SIMD: VALUBusy 36%, step 14.9us vs ~9us pipe-sum):
//  (1) REGISTER DOUBLE-BUFFERING of Wh (L2) + hv (LDS) streams: wb[2][8] +
//      hv[2][8] f32x4 prefetch k4+1 while k4's 256 FMAs issue.
//  (2) GROUP-LOCAL stage->FMA: thread group kc==p consumes ONLY producer
//      p's h chunk — the same 16 threads that stage it. One wave = one PC:
//      ds_write then s_waitcnt lgkmcnt(0) makes sibling-lane writes visible
//      with NO __syncthreads. Each wave polls only its 4 producers.
//  (3) MERGED one-pass reduction (two red regions, LDS 137 KB, fine at 1
//      block/CU): 6 barriers/step -> 4.
// FENCE-FREE cross-wg h exchange: agent-scope relaxed stores + sc0
// (L2-cached, L1-bypassed) loads. Consumer-L2 lines for out[t-1] are always
// cold before the flag-gated read, so L2 caching is safe and same-btile
// blocks on an XCD share staged lines (r0: 206 MB FETCH; r2's sc1 bypass
// cost 2.44 GB). Ordering: h stores -> vmcnt(0) -> barrier -> flag store.
__global__ __launch_bounds__(512)
__attribute__((amdgpu_waves_per_eu(2, 2)))
void lstm_persist(const float* __restrict__ Gx,
                  const float* __restrict__ Wh,
                  float* __restrict__ out,
                  unsigned* __restrict__ flags) {
    // layout (floats): red0 [32][520] = 16640 (hs[8][1152]=9216 aliases its
    // head) | red1 [32][520] = 16640 | gsum 1024.  Total 34304 fl = 137.2 KB.
    __shared__ float smem[2 * 16640 + 1024];
    float* hs   = smem;
    float* red0 = smem;
    float* red1 = smem + 16640;
    float* gsum = smem + 2 * 16640;

    const int tid   = threadIdx.x;
    const int btile = blockIdx.x >> 5;     // 0..7
    const int hct   = blockIdx.x & 31;     // 0..31
    const int b0  = btile * 8;
    const int hc0 = hct * 32;

    // matmul identity: kc = 32-k chunk (0..31), tt = 8 gate-cols (0..15)
    const int kc = tid >> 4;
    const int tt = tid & 15;
    const int gate_m = tt >> 2;            // 0..3
    const int sub8 = (tt & 3) * 8;         // 0,8,16,24 within the 32-col block
    const float* wbase = Wh + (size_t)(kc * 32) * G4 + gate_m * HH + hc0 + sub8;

    // staging identity: 16 threads per producer (same 16 that FMA chunk pp)
    const int pp  = kc;                    // producer 0..31 == own k-chunk
    const int srow = tt >> 1;              // 0..7 local b row
    const int cq0  = (tt & 1) * 4;         // first of 4 consecutive f32x4 slots

    // cell identity (tid<256): one (b, hcol) cell per thread, c in creg
    const bool cell_act = (tid < 256);
    const int cb  = tid >> 5;              // 0..7 local b (tid<256)
    const int chc = tid & 31;              // 0..31 local h col
    const size_t cell_g = (size_t)(b0 + cb) * G4 + hc0 + chc;
    const size_t cell_h = (size_t)(b0 + cb) * HH + hc0 + chc;
    float creg = 0.0f;

    // reduction reader identity: 512 readers, two (b, gate-col) sums each
    const int rb_ = tid >> 7;              // 0..3
    const int rgc = tid & 127;             // gate-col 0..127 (= tt*8 + j)
    const int rtt = rgc >> 3;              // writer tt
    const int rj  = rgc & 7;               // writer j

    unsigned* gflags = flags + btile * 32; // this btile group's 32 flags

    // ---- t = 0: gates = Gx[0] (h0 = c0 = 0); publish h(0) through IC
    if (cell_act) {
        const float* gr = Gx + cell_g;
        float ii = hsig(gr[0]);
        float gv = htanh(gr[2 * HH]);
        float oo = hsig(gr[3 * HH]);
        creg = ii * gv;
        __hip_atomic_store(out + cell_h, oo * htanh(creg),
                           __ATOMIC_RELAXED, __HIP_MEMORY_SCOPE_AGENT);
    }
    asm volatile("s_waitcnt vmcnt(0)" ::: "memory");
    __syncthreads();
    if (tid == 0)
        __hip_atomic_store(gflags + hct, 1u, __ATOMIC_RELAXED,
                           __HIP_MEMORY_SCOPE_AGENT);

    for (int t = 1; t < TT; ++t) {
        // prefetch this step's Gx gate values (own data; overlaps the wait)
        float gi = 0.f, gf = 0.f, gg = 0.f, go = 0.f;
        if (cell_act) {
            const float* gr = Gx + (size_t)t * BB * G4 + cell_g;
            gi = gr[0];
            gf = gr[HH];
            gg = gr[2 * HH];
            go = gr[3 * HH];
        }

        float acc[8][8] = {};
        f32x4 wb0[8], wb1[8], hv0[8], hv1[8];

        // w is h-independent: issue k4=0's Wh loads BEFORE the flag poll —
        // full L2 latency hides under poll+stage.
        LOADW(wb0, 0);

        // ---- group-local: poll OWN producer's flag (4 producers per wave)
        while (__hip_atomic_load(gflags + pp, __ATOMIC_RELAXED,
                                 __HIP_MEMORY_SCOPE_AGENT) < (unsigned)t)
            __builtin_amdgcn_s_sleep(1);

        // ---- stage own 64B slice of chunk pp (4 x 16B sc0, L2-cached)
        {
            const float* hp = out + (size_t)(t - 1) * BH
                            + (size_t)(b0 + srow) * HH + pp * 32 + cq0 * 4;
            f32x4 v0, v1, v2, v3;
            asm volatile(
                "global_load_dwordx4 %0, %4, off sc0\n\t"
                "global_load_dwordx4 %1, %4, off offset:16 sc0\n\t"
                "global_load_dwordx4 %2, %4, off offset:32 sc0\n\t"
                "global_load_dwordx4 %3, %4, off offset:48 sc0\n\t"
                "s_waitcnt vmcnt(0)"
                : "=&v"(v0), "=&v"(v1), "=&v"(v2), "=&v"(v3)
                : "v"(hp)
                : "memory");
            float* hd = &hs[srow * 1152 + pp * 36 + cq0 * 4];
            *(f32x4*)(hd)      = v0;
            *(f32x4*)(hd + 4)  = v1;
            *(f32x4*)(hd + 8)  = v2;
            *(f32x4*)(hd + 12) = v3;
        }
        // wave-internal visibility: one PC per wave -> all 64 lanes' ds_write
        // retired after lgkmcnt(0). No block barrier needed (group p reads
        // ONLY chunk p, which group p itself staged).
        asm volatile("s_waitcnt lgkmcnt(0)" ::: "memory");
        __builtin_amdgcn_sched_barrier(0);

        // ---- FMA: acc[8 b][8 gc] over k in [kc*32, kc*32+32), double-
        // buffered register streams for both Wh (L2) and hv (LDS).
        LOADH(hv0, 0);
        #pragma unroll 1
        for (int kk = 0; kk < 4; ++kk) {
            LOADW(wb1, kk * 2 + 1);
            LOADH(hv1, kk * 2 + 1);
            FMA8(wb0, hv0);
            if (kk < 3) {
                LOADW(wb0, kk * 2 + 2);
                LOADH(hv0, kk * 2 + 2);
            }
            FMA8(wb1, hv1);
        }
        __syncthreads();                   // F: hs dead; smem becomes red

        // ---- merged one-pass reduce: write all 64 partials (both halves),
        // one barrier, gather both. write red[vidx][tid]: consecutive-tid,
        // conflict-free. read stride 16, RPAD%32==8 -> 2-way = free.
        #pragma unroll
        for (int bi = 0; bi < 4; ++bi)
            #pragma unroll
            for (int j = 0; j < 8; ++j) {
                red0[(size_t)(bi * 8 + j) * RPAD + tid] = acc[bi][j];
                red1[(size_t)(bi * 8 + j) * RPAD + tid] = acc[4 + bi][j];
            }
        __syncthreads();                   // W
        {
            const float* rp0 = red0 + (size_t)(rb_ * 8 + rj) * RPAD + rtt;
            const float* rp1 = red1 + (size_t)(rb_ * 8 + rj) * RPAD + rtt;
            float a0 = 0.f, a1 = 0.f, a2 = 0.f, a3 = 0.f;
            float c0 = 0.f, c1 = 0.f, c2 = 0.f, c3 = 0.f;
            #pragma unroll
            for (int k2 = 0; k2 < 32; k2 += 4) {
                a0 += rp0[(k2 + 0) * 16];
                a1 += rp0[(k2 + 1) * 16];
                a2 += rp0[(k2 + 2) * 16];
                a3 += rp0[(k2 + 3) * 16];
                c0 += rp1[(k2 + 0) * 16];
                c1 += rp1[(k2 + 1) * 16];
                c2 += rp1[(k2 + 2) * 16];
                c3 += rp1[(k2 + 3) * 16];
            }
            gsum[rb_ * 128 + rgc]       = (a0 + a1) + (a2 + a3);
            gsum[(4 + rb_) * 128 + rgc] = (c0 + c1) + (c2 + c3);
        }
        __syncthreads();                   // G

        // ---- cell update (thread-local c); publish h through IC
        if (cell_act) {
            float ii = hsig(gi + gsum[cb * 128 + chc]);
            float ff = hsig(gf + gsum[cb * 128 + 32 + chc]);
            float gv = htanh(gg + gsum[cb * 128 + 64 + chc]);
            float oo = hsig(go + gsum[cb * 128 + 96 + chc]);
            creg = ff * creg + ii * gv;
            __hip_atomic_store(out + (size_t)t * BH + cell_h, oo * htanh(creg),
                               __ATOMIC_RELAXED, __HIP_MEMORY_SCOPE_AGENT);
        }
        asm volatile("s_waitcnt vmcnt(0)" ::: "memory");
        __syncthreads();                   // P
        if (tid == 0)
            __hip_atomic_store(gflags + hct, (unsigned)(t + 1),
                               __ATOMIC_RELAXED, __HIP_MEMORY_SCOPE_AGENT);
    }
}

// ---------------------------------------------------------------------------
extern "C" void kernel_launch(void* const* d_in, const int* in_sizes, int n_in,
                              void* d_out, int out_size, void* d_ws, size_t ws_size,
                              hipStream_t stream) {
    const float* x  = (const float*)d_in[0];   // [T,B,D]
    const float* Wx = (const float*)d_in[1];   // [D,4H]
    const float* Wh = (const float*)d_in[2];   // [H,4H]
    const float* bs = (const float*)d_in[3];   // [4H]
    float* out = (float*)d_out;                // [T,B,H] — doubles as h history

    // ws layout (floats): Gx 33,554,432 | flags (256 u32)
    float* Gx = (float*)d_ws;
    unsigned* flags = (unsigned*)(Gx + (size_t)MM * G4);

    zero_bar<<<dim3(1), dim3(256), 0, stream>>>(flags);

    // Gx = X @ Wx + b for all timesteps at once
    gx_gemm<<<dim3(G4 / 128, MM / 128), dim3(256), 0, stream>>>(x, Wx, bs, Gx);

    // all 128 recurrent steps in one plain-launch persistent kernel
    lstm_persist<<<dim3(NWG), dim3(512), 0, stream>>>(Gx, Wh, out, flags);
}

// Round 10
// 2772.477 us; speedup vs baseline: 1.3094x; 1.2573x over previous
//
#include <hip/hip_runtime.h>

// Problem constants: T=128, B=64, D=1024, H=1024. fp32 throughout (the
// recurrence is chaotic: per-step gate noise amplifies ~1e3x over 128 steps;
// fp32 order-noise lands at ~4e-3 absmax, bf16 would fail the 2e-2 gate).
#define TT 128
#define BB 64
#define DD 1024
#define HH 1024
#define G4 4096          // 4*H
#define BH (BB*HH)       // 65536, one timestep of h/out

#define NWG 256          // persistent grid: 1 block per CU (r0/r4 partition —
                         // r1/r3 proved co-resident same-domain blocks
                         // phase-lock and contend without overlap)
#define RPAD 520         // red row pad: 520%32==8 -> reader gather 2-way (free)

typedef float f32x4 __attribute__((ext_vector_type(4)));

__device__ __forceinline__ float hsig(float x) {
    x += 0.5f;
    return fminf(fmaxf(x, 0.0f), 1.0f);
}
__device__ __forceinline__ float htanh(float x) {
    return fminf(fmaxf(x, -1.0f), 1.0f);
}

// ---------------------------------------------------------------------------
__global__ void zero_bar(unsigned* p) {
    p[threadIdx.x] = 0u;   // flags[256]
}

// ---------------------------------------------------------------------------
// FMA over the staged, skewed [8][1024] LDS region (hs) with weight base WB.
// Identical structure for the h-matmul (WB=Wh panel) and x-matmul (WB=Wx
// panel): thread (kc,tt) accumulates acc[8 rows][8 gate-cols] over its
// 32-k chunk. r0/r4-proven codegen.
#define FMA_PHASE(WB)                                                      \
    {   const float* wp = (WB);                                            \
        _Pragma("unroll 2")                                                \
        for (int k4 = 0; k4 < 8; ++k4) {                                   \
            f32x4 hv[8];                                                   \
            _Pragma("unroll")                                              \
            for (int bi = 0; bi < 8; ++bi)                                 \
                hv[bi] = *(const f32x4*)&hs[bi * 1152 + kc * 36 + k4 * 4]; \
            _Pragma("unroll")                                              \
            for (int j = 0; j < 4; ++j) {                                  \
                f32x4 w0 = *(const f32x4*)(wp);                            \
                f32x4 w1 = *(const f32x4*)(wp + 4);                        \
                wp += G4;                                                  \
                _Pragma("unroll")                                          \
                for (int bi = 0; bi < 8; ++bi) {                           \
                    float h = hv[bi][j];                                   \
                    acc[bi][0] += h * w0[0];                               \
                    acc[bi][1] += h * w0[1];                               \
                    acc[bi][2] += h * w0[2];                               \
                    acc[bi][3] += h * w0[3];                               \
                    acc[bi][4] += h * w1[0];                               \
                    acc[bi][5] += h * w1[1];                               \
                    acc[bi][6] += h * w1[2];                               \
                    acc[bi][7] += h * w1[3];                               \
                } } } }

// Two-round conflict-free reduce (r3/r4-proven): acc partials -> red -> gsum.
// write red[vidx][tid]: consecutive-tid, conflict-free. read stride 16,
// RPAD%32==8 -> every bank hit by exactly 2 lanes (free). gsum gc layout =
// gate*32 + chc.
#define REDUCE_PHASE()                                                     \
    _Pragma("unroll")                                                      \
    for (int round = 0; round < 2; ++round) {                              \
        _Pragma("unroll")                                                  \
        for (int bi = 0; bi < 4; ++bi)                                     \
            _Pragma("unroll")                                              \
            for (int j = 0; j < 8; ++j)                                    \
                red[(size_t)(bi * 8 + j) * RPAD + tid] =                   \
                    acc[round * 4 + bi][j];                                \
        __syncthreads();                                                   \
        {   const float* rp = red + (size_t)(rb_ * 8 + rj) * RPAD + rtt;   \
            float s0 = 0.f, s1 = 0.f, s2 = 0.f, s3 = 0.f;                  \
            _Pragma("unroll")                                              \
            for (int k2 = 0; k2 < 32; k2 += 4) {                           \
                s0 += rp[(k2 + 0) * 16];                                   \
                s1 += rp[(k2 + 1) * 16];                                   \
                s2 += rp[(k2 + 2) * 16];                                   \
                s3 += rp[(k2 + 3) * 16];                                   \
            }                                                              \
            gsum[(round * 4 + rb_) * 128 + rgc] = (s0 + s1) + (s2 + s3);   \
        }                                                                  \
        __syncthreads();                                                   \
    }

// Stage X[TIDX][b0..b0+7][0..1023] into the skewed hs region (xs role).
// Thread: row=tid>>6, chunk=tid&63 -> 16 consecutive floats; global loads
// perfectly coalesced (wave = one full row). X is read-only input: plain
// cached loads, no coherence protocol needed. Each 16-float chunk is
// 16-aligned -> stays inside one 32-float skew group (stride 36).
#define STAGE_X(TIDX)                                                      \
    {   const float* xr = X + ((size_t)(TIDX) * BB + b0 + xrow) * DD       \
                        + xchunk * 16;                                     \
        f32x4 a0 = *(const f32x4*)(xr);                                    \
        f32x4 a1 = *(const f32x4*)(xr + 4);                                \
        f32x4 a2 = *(const f32x4*)(xr + 8);                                \
        f32x4 a3 = *(const f32x4*)(xr + 12);                               \
        int k0_ = xchunk * 16;                                             \
        float* xd = &hs[xrow * 1152 + (k0_ >> 5) * 36 + (k0_ & 31)];       \
        *(f32x4*)(xd)      = a0;                                           \
        *(f32x4*)(xd + 4)  = a1;                                           \
        *(f32x4*)(xd + 8)  = a2;                                           \
        *(f32x4*)(xd + 12) = a3;                                           \
    }

// Compute this block's OWN x-gates for timestep TIDX (the self-contained
// gemm fusion): stage X -> FMA vs Wx panel -> reduce -> xg regs (+bias).
// Runs AFTER publishing h(t) + flag, filling the peer-straggler window.
#define XGATES(TIDX)                                                       \
    {   STAGE_X(TIDX);                                                     \
        __syncthreads();                                                   \
        float acc[8][8] = {};                                              \
        FMA_PHASE(wbase_x);                                                \
        __syncthreads();                                                   \
        REDUCE_PHASE();                                                    \
        if (cell_act) {                                                    \
            xg[0] = gsum[cb * 128 + chc]      + bR[0];                     \
            xg[1] = gsum[cb * 128 + 32 + chc] + bR[1];                     \
            xg[2] = gsum[cb * 128 + 64 + chc] + bR[2];                     \
            xg[3] = gsum[cb * 128 + 96 + chc] + bR[3];                     \
        } }

// ---------------------------------------------------------------------------
// Fully-fused persistent LSTM: the recurrence AND the x-projection in one
// 256-block kernel. (RESUBMISSION of r9 — container-acquisition failure, no
// bench verdict; design re-audited: sync surface identical to r4's 5-clean-
// round structure, all LDS indices bounds-checked, liveness ~110 < 128 cap.)
//
// r4's persist structure (best measured: 1856-1970us for the recurrence
// alone) is kept VERBATIM; the 550us serial gx_gemm prologue is replaced by
// a per-block lookahead x-phase:
//   block (btile,hct) consumes exactly Gx[t][its 8 rows][its 128 gate-cols]
//   -> it computes that slice ITSELF one step ahead (X rows staged to LDS,
//   Wx panel from L2, same FMA+reduce machinery as the h-matmul), keeping
//   the result in 4 regs/cell-thread. Zero new cross-block sync; dispatch-
//   order-independent; deadlock surface identical to r4.
//   No Gx array -> -134MB write -134MB read of workspace traffic.
// Placement: XGATES(t+1) runs after publish+flag of h(t) — it overlaps the
// cross-XCD flag/h propagation + peer straggle that r4 spent spinning (r4:
// VALUBusy 36%, step 14.9us vs ~9us pipe-sum).
// L2 locality: bid%8 round-robin -> each XCD hosts 4 distinct hct panels:
// Wh 4x512KB + Wx 4x512KB = 4MB ~= L2 capacity.
// FENCE-FREE cross-wg h exchange (r0-proven): agent-scope relaxed stores +
// sc0 (L2-cached, L1-bypassed) loads; consumer L2 lines for out[t-1] always
// cold before the flag-gated read. Ordering: h stores -> vmcnt(0) ->
// barrier -> flag store.
// VGPR-CAP LADDER (r1-r7, closed): the allocator cap is 128 and cannot be
// raised ((512,4)->64, (512,2)->128, (512,1)->128, waves_per_eu inert).
// This design needs NO register pipeline: phases are sequential, acc[8][8]
// is reused by both matmuls; peak liveness ~110 < 128.
__global__ __launch_bounds__(512) void lstm_persist(const float* __restrict__ X,
                                                    const float* __restrict__ Wx,
                                                    const float* __restrict__ bias,
                                                    const float* __restrict__ Wh,
                                                    float* __restrict__ out,
                                                    unsigned* __restrict__ flags) {
    // one 16640-float region multiplexed as hs(h)/xs(x)/red + gsum[1024].
    // 17664 floats = 70.7 KB (r4's exact footprint).
    __shared__ float smem[16640 + 1024];
    float* hs   = smem;
    float* red  = smem;
    float* gsum = smem + 16640;

    const int tid   = threadIdx.x;
    const int btile = blockIdx.x >> 5;     // 0..7
    const int hct   = blockIdx.x & 31;     // 0..31
    const int b0  = btile * 8;
    const int hc0 = hct * 32;

    // matmul identity (r0-proven): kc = 32-k chunk (0..31), tt = 8 gate-cols
    const int kc = tid >> 4;
    const int tt = tid & 15;
    const int gate_m = tt >> 2;            // 0..3
    const int sub8 = (tt & 3) * 8;         // 0,8,16,24 within the 32-col block
    const float* wbase_h = Wh + (size_t)(kc * 32) * G4 + gate_m * HH + hc0 + sub8;
    const float* wbase_x = Wx + (size_t)(kc * 32) * G4 + gate_m * HH + hc0 + sub8;

    // h staging identity: 16 threads per producer, 64B contiguous each
    const int pp  = tid >> 4;              // producer 0..31
    const int ss  = tid & 15;
    const int srow = ss >> 1;              // 0..7 local b row
    const int cq0  = (ss & 1) * 4;         // first of 4 consecutive f32x4 slots

    // x staging identity: 64 threads per row, 16 floats each
    const int xrow   = tid >> 6;           // 0..7 local b row
    const int xchunk = tid & 63;           // 16-float chunk within the row

    // cell identity (tid<256): one (b, hcol) cell per thread, c in creg
    const bool cell_act = (tid < 256);
    const int cb  = tid >> 5;              // 0..7 local b
    const int chc = tid & 31;              // 0..31 local h col
    const size_t cell_h = (size_t)(b0 + cb) * HH + hc0 + chc;
    float creg = 0.0f;

    // reduction reader identity: 512 readers, one (b, gate-col) sum each
    const int rb_ = tid >> 7;              // 0..3 round-local b
    const int rgc = tid & 127;             // gate-col 0..127
    const int rtt = rgc >> 3;              // writer tt
    const int rj  = rgc & 7;               // writer j

    unsigned* gflags = flags + btile * 32; // this btile group's 32 h-flags

    // bias (4 regs, cell threads) + lookahead x-gates (4 regs)
    float bR[4] = {0.f, 0.f, 0.f, 0.f};
    float xg[4] = {0.f, 0.f, 0.f, 0.f};
    if (cell_act) {
        bR[0] = bias[hc0 + chc];
        bR[1] = bias[HH + hc0 + chc];
        bR[2] = bias[2 * HH + hc0 + chc];
        bR[3] = bias[3 * HH + hc0 + chc];
    }

    // ---- prologue: xg = xgates(0); t=0 cell (h0=c0=0); publish h(0)
    XGATES(0);
    if (cell_act) {
        float ii = hsig(xg[0]);
        float gv = htanh(xg[2]);
        float oo = hsig(xg[3]);
        creg = ii * gv;
        __hip_atomic_store(out + cell_h, oo * htanh(creg),
                           __ATOMIC_RELAXED, __HIP_MEMORY_SCOPE_AGENT);
    }
    asm volatile("s_waitcnt vmcnt(0)" ::: "memory");
    __syncthreads();
    if (tid == 0)
        __hip_atomic_store(gflags + hct, 1u, __ATOMIC_RELAXED,
                           __HIP_MEMORY_SCOPE_AGENT);

    // xgates(1) — computed while peer blocks finish their t=0
    XGATES(1);

    for (int t = 1; t < TT; ++t) {
        // ---- streamed stage: poll OWN producer's flag, then immediately
        // load this thread's 64B slice (4 x 16B sc0, L2-cached) -> skewed hs.
        {
            while (__hip_atomic_load(gflags + pp, __ATOMIC_RELAXED,
                                     __HIP_MEMORY_SCOPE_AGENT) < (unsigned)t)
                __builtin_amdgcn_s_sleep(1);

            const float* hp = out + (size_t)(t - 1) * BH
                            + (size_t)(b0 + srow) * HH + pp * 32 + cq0 * 4;
            f32x4 v0, v1, v2, v3;
            asm volatile(
                "global_load_dwordx4 %0, %4, off sc0\n\t"
                "global_load_dwordx4 %1, %4, off offset:16 sc0\n\t"
                "global_load_dwordx4 %2, %4, off offset:32 sc0\n\t"
                "global_load_dwordx4 %3, %4, off offset:48 sc0\n\t"
                "s_waitcnt vmcnt(0)"
                : "=&v"(v0), "=&v"(v1), "=&v"(v2), "=&v"(v3)
                : "v"(hp)
                : "memory");
            float* hd = &hs[srow * 1152 + pp * 36 + cq0 * 4];
            *(f32x4*)(hd)      = v0;
            *(f32x4*)(hd + 4)  = v1;
            *(f32x4*)(hd + 8)  = v2;
            *(f32x4*)(hd + 12) = v3;
        }
        __syncthreads();

        // ---- h-matmul + reduce (r4 verbatim)
        {
            float acc[8][8] = {};
            FMA_PHASE(wbase_h);
            __syncthreads();               // hs dead; smem becomes red
            REDUCE_PHASE();
        }

        // ---- cell update: gates = xg (lookahead x-proj + bias) + h-proj
        if (cell_act) {
            float ii = hsig(xg[0] + gsum[cb * 128 + chc]);
            float ff = hsig(xg[1] + gsum[cb * 128 + 32 + chc]);
            float gv = htanh(xg[2] + gsum[cb * 128 + 64 + chc]);
            float oo = hsig(xg[3] + gsum[cb * 128 + 96 + chc]);
            creg = ff * creg + ii * gv;
            __hip_atomic_store(out + (size_t)t * BH + cell_h, oo * htanh(creg),
                               __ATOMIC_RELAXED, __HIP_MEMORY_SCOPE_AGENT);
        }
        asm volatile("s_waitcnt vmcnt(0)" ::: "memory");
        __syncthreads();
        if (tid == 0)
            __hip_atomic_store(gflags + hct, (unsigned)(t + 1),
                               __ATOMIC_RELAXED, __HIP_MEMORY_SCOPE_AGENT);

        // ---- lookahead: xgates(t+1) AFTER publish+flag — overlaps the
        // cross-XCD flag propagation and peer-straggler window.
        if (t < TT - 1) {
            XGATES(t + 1);
        }
    }
}

// ---------------------------------------------------------------------------
extern "C" void kernel_launch(void* const* d_in, const int* in_sizes, int n_in,
                              void* d_out, int out_size, void* d_ws, size_t ws_size,
                              hipStream_t stream) {
    const float* x  = (const float*)d_in[0];   // [T,B,D]
    const float* Wx = (const float*)d_in[1];   // [D,4H]
    const float* Wh = (const float*)d_in[2];   // [H,4H]
    const float* bs = (const float*)d_in[3];   // [4H]
    float* out = (float*)d_out;                // [T,B,H] — doubles as h history

    // ws layout: flags (256 u32) only — the Gx workspace is GONE (each block
    // computes its own x-gate slice in-kernel).
    unsigned* flags = (unsigned*)d_ws;

    zero_bar<<<dim3(1), dim3(256), 0, stream>>>(flags);

    // everything — x-projection AND all 128 recurrent steps — in one
    // plain-launch persistent kernel.
    lstm_persist<<<dim3(NWG), dim3(512), 0, stream>>>(x, Wx, bs, Wh, out,
                                                      flags);
}

// Round 11
// 2361.672 us; speedup vs baseline: 1.5372x; 1.1739x over previous
//
#include <hip/hip_runtime.h>

// Problem constants: T=128, B=64, D=1024, H=1024. fp32 throughout (the
// recurrence is chaotic: per-step gate noise amplifies ~1e3x over 128 steps;
// fp32 order-noise lands at ~4e-3 absmax, bf16 would fail the 2e-2 gate).
#define TT 128
#define BB 64
#define DD 1024
#define HH 1024
#define G4 4096          // 4*H
#define MM (TT*BB)       // 8192 rows of X flattened
#define BH (BB*HH)       // 65536, one timestep of h/out

#define NWG 256          // persistent grid: 1 block per CU (r0/r4 partition —
                         // r1/r3 proved co-resident same-domain blocks
                         // phase-lock and contend without overlap; r9/r10
                         // proved symmetric fused work cannot overlap either)
#define RPAD 520         // red row pad: 520%32==8 -> reader gather 2-way (free)

typedef float f32x4 __attribute__((ext_vector_type(4)));

__device__ __forceinline__ float hsig(float x) {
    x += 0.5f;
    return fminf(fmaxf(x, 0.0f), 1.0f);
}
__device__ __forceinline__ float htanh(float x) {
    return fminf(fmaxf(x, -1.0f), 1.0f);
}

// ---------------------------------------------------------------------------
__global__ void zero_bar(unsigned* p) {
    p[threadIdx.x] = 0u;   // per-wave flags: 256 blocks x 4 waves = 1024
}

// ---------------------------------------------------------------------------
// Gx[8192][4096] = X[8192][1024] @ Wx[1024][4096] + bias  (proven, ~550 us =
// ~80% of fp32 vector peak; r10 proved fusing it into persist thrashes L2
// and serializes — keep it as a separate kernel)
__global__ __launch_bounds__(256) void gx_gemm(const float* __restrict__ X,
                                               const float* __restrict__ W,
                                               const float* __restrict__ bias,
                                               float* __restrict__ C) {
    __shared__ float As[16][132];
    __shared__ float Bs[16][132];

    const int tid = threadIdx.x;
    const int tx = tid & 15;
    const int ty = tid >> 4;
    const int m0 = blockIdx.y * 128;
    const int n0 = blockIdx.x * 128;

    float acc[8][8] = {};
    float4 ra[2], rb[2];

    #pragma unroll
    for (int i = 0; i < 2; ++i) {
        int f4 = tid + i * 256;
        ra[i] = *(const float4*)(X + (size_t)(m0 + (f4 >> 2)) * DD + (f4 & 3) * 4);
        rb[i] = *(const float4*)(W + (size_t)(f4 >> 5) * G4 + n0 + (f4 & 31) * 4);
    }

    for (int k0 = 0; k0 < DD; k0 += 16) {
        #pragma unroll
        for (int i = 0; i < 2; ++i) {
            int f4 = tid + i * 256;
            int mi = f4 >> 2, kq = f4 & 3;
            As[kq * 4 + 0][mi] = ra[i].x;
            As[kq * 4 + 1][mi] = ra[i].y;
            As[kq * 4 + 2][mi] = ra[i].z;
            As[kq * 4 + 3][mi] = ra[i].w;
            *(float4*)&Bs[f4 >> 5][(f4 & 31) * 4] = rb[i];
        }
        __syncthreads();

        const int kn = (k0 + 16 < DD) ? (k0 + 16) : k0;
        #pragma unroll
        for (int i = 0; i < 2; ++i) {
            int f4 = tid + i * 256;
            ra[i] = *(const float4*)(X + (size_t)(m0 + (f4 >> 2)) * DD + kn + (f4 & 3) * 4);
            rb[i] = *(const float4*)(W + (size_t)(kn + (f4 >> 5)) * G4 + n0 + (f4 & 31) * 4);
        }

        #pragma unroll
        for (int kk = 0; kk < 16; ++kk) {
            float ar[8], br[8];
            *(float4*)&ar[0] = *(const float4*)&As[kk][ty * 4];
            *(float4*)&ar[4] = *(const float4*)&As[kk][64 + ty * 4];
            *(float4*)&br[0] = *(const float4*)&Bs[kk][tx * 4];
            *(float4*)&br[4] = *(const float4*)&Bs[kk][64 + tx * 4];
            #pragma unroll
            for (int i = 0; i < 8; ++i)
                #pragma unroll
                for (int j = 0; j < 8; ++j)
                    acc[i][j] += ar[i] * br[j];
        }
        __syncthreads();
    }

    float bl[8];
    *(float4*)&bl[0] = *(const float4*)(bias + n0 + tx * 4);
    *(float4*)&bl[4] = *(const float4*)(bias + n0 + 64 + tx * 4);
    #pragma unroll
    for (int i = 0; i < 8; ++i) {
        int mrow = m0 + ty * 4 + (i & 3) + 64 * (i >> 2);
        float* crow = C + (size_t)mrow * G4 + n0;
        float4 o1, o2;
        o1.x = acc[i][0] + bl[0]; o1.y = acc[i][1] + bl[1];
        o1.z = acc[i][2] + bl[2]; o1.w = acc[i][3] + bl[3];
        o2.x = acc[i][4] + bl[4]; o2.y = acc[i][5] + bl[5];
        o2.z = acc[i][6] + bl[6]; o2.w = acc[i][7] + bl[7];
        *(float4*)(crow + tx * 4) = o1;
        *(float4*)(crow + 64 + tx * 4) = o2;
    }
}

// ---------------------------------------------------------------------------
// Persistent recurrence — r4 base (best measured: 1856-1970us) with three
// latency cuts, no new register demand (VGPR-cap ladder r1-r7: 128 hard):
//  (1) MERGED one-pass reduction (correctness field-proven in r5/6/7): write
//      both 4-row halves to red0/red1, ONE barrier, each thread gathers two
//      sums. Barriers/step: 6 -> 4. LDS 137 KB (1 block/CU proven r5-r7).
//  (2) PER-WAVE SPLIT PUBLISH: consumer slice (producer pp, row srow) is
//      produced entirely by cell wave w=srow>>1 of block pp. Lane 0 of each
//      cell wave sets its OWN flag right after its s_waitcnt vmcnt(0) —
//      the producer's tail barrier + tid0-flag leave the consumer's
//      critical path. Ordering per wave: h stores (sc0 sc1, write-through
//      IC) -> vmcnt(0) -> flag store. Same protocol, finer grain.
//  (3) NO END-OF-STEP BARRIER: after the gather barrier G, waves race ahead
//      to poll+stage t+1 while cell waves finish cell-math+publish. Audited:
//      hs(≡red0 head) reads all complete before G; gsum is non-aliased and
//      cell waves read it before stage(t+1)'s S barrier; staging reads of
//      out[t] are flag-gated; intra-block self-staging polls the own-block
//      per-wave flag, set before the cell wave itself stages.
// FENCE-FREE cross-wg h exchange (r0-proven): agent-scope relaxed stores +
// sc0 (L2-cached, L1-bypassed) loads; consumer L2 lines for out[t-1] always
// cold before the flag-gated read (r2's sc1-bypass cost 2.44GB FETCH).
__global__ __launch_bounds__(512) void lstm_persist(const float* __restrict__ Gx,
                                                    const float* __restrict__ Wh,
                                                    float* __restrict__ out,
                                                    unsigned* __restrict__ flags) {
    // layout (floats): red0 [32][520] = 16640 (hs[8][1152]=9216 aliases its
    // head) | red1 [32][520] = 16640 | gsum 1024.  Total 34304 fl = 137.2 KB.
    __shared__ float smem[2 * 16640 + 1024];
    float* hs   = smem;
    float* red0 = smem;
    float* red1 = smem + 16640;
    float* gsum = smem + 2 * 16640;

    const int tid   = threadIdx.x;
    const int btile = blockIdx.x >> 5;     // 0..7
    const int hct   = blockIdx.x & 31;     // 0..31
    const int b0  = btile * 8;
    const int hc0 = hct * 32;

    // matmul identity (r0-proven): kc = 32-k chunk (0..31), tt = 8 gate-cols
    const int kc = tid >> 4;
    const int tt = tid & 15;
    const int gate_m = tt >> 2;            // 0..3
    const int sub8 = (tt & 3) * 8;         // 0,8,16,24 within the 32-col block
    const float* wbase = Wh + (size_t)(kc * 32) * G4 + gate_m * HH + hc0 + sub8;

    // staging identity: 16 threads per producer, 64B contiguous each
    const int pp  = tid >> 4;              // producer 0..31
    const int ss  = tid & 15;
    const int srow = ss >> 1;              // 0..7 local b row
    const int cq0  = (ss & 1) * 4;         // first of 4 consecutive f32x4 slots

    // cell identity (tid<256): one (b, hcol) cell per thread, c in creg
    const bool cell_act = (tid < 256);
    const int cb  = tid >> 5;              // 0..7 local b
    const int chc = tid & 31;              // 0..31 local h col
    const size_t cell_g = (size_t)(b0 + cb) * G4 + hc0 + chc;
    const size_t cell_h = (size_t)(b0 + cb) * HH + hc0 + chc;
    float creg = 0.0f;

    // reduction reader identity: 512 readers, two (b, gate-col) sums each
    const int rb_ = tid >> 7;              // 0..3
    const int rgc = tid & 127;             // gate-col 0..127 (= tt*8 + j)
    const int rtt = rgc >> 3;              // writer tt
    const int rj  = rgc & 7;               // writer j

    // per-wave flags: 4 per block. consumer polls the wave that produced its
    // slice (w = srow>>1); producer cell wave (tid>>6 in 0..3) sets its own.
    unsigned* bflags = flags + btile * 128;          // 32 producers x 4 waves
    unsigned* pollp  = bflags + pp * 4 + (srow >> 1);
    unsigned* myflag = bflags + hct * 4 + (tid >> 6);

    // ---- t = 0: gates = Gx[0] (h0 = c0 = 0); publish h(0); per-wave flag
    if (cell_act) {
        const float* gr = Gx + cell_g;
        float ii = hsig(gr[0]);
        float gv = htanh(gr[2 * HH]);
        float oo = hsig(gr[3 * HH]);
        creg = ii * gv;
        __hip_atomic_store(out + cell_h, oo * htanh(creg),
                           __ATOMIC_RELAXED, __HIP_MEMORY_SCOPE_AGENT);
        asm volatile("s_waitcnt vmcnt(0)" ::: "memory");
        if ((tid & 63) == 0)
            __hip_atomic_store(myflag, 1u, __ATOMIC_RELAXED,
                               __HIP_MEMORY_SCOPE_AGENT);
    }
    // no barrier: t=1 staging writes hs fresh; remote reads are flag-gated.

    for (int t = 1; t < TT; ++t) {
        // prefetch this step's Gx gate values (own data; overlaps the wait)
        float gi = 0.f, gf = 0.f, gg = 0.f, go = 0.f;
        if (cell_act) {
            const float* gr = Gx + (size_t)t * BB * G4 + cell_g;
            gi = gr[0];
            gf = gr[HH];
            gg = gr[2 * HH];
            go = gr[3 * HH];
        }

        // ---- streamed stage: poll the producing WAVE's flag, then load
        // this thread's 64B slice (4 x 16B sc0, L2-cached) -> skewed hs.
        {
            while (__hip_atomic_load(pollp, __ATOMIC_RELAXED,
                                     __HIP_MEMORY_SCOPE_AGENT) < (unsigned)t)
                __builtin_amdgcn_s_sleep(1);

            const float* hp = out + (size_t)(t - 1) * BH
                            + (size_t)(b0 + srow) * HH + pp * 32 + cq0 * 4;
            f32x4 v0, v1, v2, v3;
            asm volatile(
                "global_load_dwordx4 %0, %4, off sc0\n\t"
                "global_load_dwordx4 %1, %4, off offset:16 sc0\n\t"
                "global_load_dwordx4 %2, %4, off offset:32 sc0\n\t"
                "global_load_dwordx4 %3, %4, off offset:48 sc0\n\t"
                "s_waitcnt vmcnt(0)"
                : "=&v"(v0), "=&v"(v1), "=&v"(v2), "=&v"(v3)
                : "v"(hp)
                : "memory");
            float* hd = &hs[srow * 1152 + pp * 36 + cq0 * 4];
            *(f32x4*)(hd)      = v0;
            *(f32x4*)(hd + 4)  = v1;
            *(f32x4*)(hd + 8)  = v2;
            *(f32x4*)(hd + 12) = v3;
        }
        __syncthreads();                   // S: stage complete

        // ---- FMA: acc[8 b][8 gc] over k in [kc*32, kc*32+32)  (r0-proven)
        float acc[8][8] = {};
        const float* wp = wbase;
        #pragma unroll 2
        for (int k4 = 0; k4 < 8; ++k4) {
            f32x4 hv[8];
            #pragma unroll
            for (int bi = 0; bi < 8; ++bi)
                hv[bi] = *(const f32x4*)&hs[bi * 1152 + kc * 36 + k4 * 4];
            #pragma unroll
            for (int j = 0; j < 4; ++j) {
                f32x4 w0 = *(const f32x4*)(wp);
                f32x4 w1 = *(const f32x4*)(wp + 4);
                wp += G4;
                #pragma unroll
                for (int bi = 0; bi < 8; ++bi) {
                    float h = hv[bi][j];
                    acc[bi][0] += h * w0[0];
                    acc[bi][1] += h * w0[1];
                    acc[bi][2] += h * w0[2];
                    acc[bi][3] += h * w0[3];
                    acc[bi][4] += h * w1[0];
                    acc[bi][5] += h * w1[1];
                    acc[bi][6] += h * w1[2];
                    acc[bi][7] += h * w1[3];
                }
            }
        }
        __syncthreads();                   // F: hs dead; smem becomes red

        // ---- merged one-pass reduce (r5-proven correctness): write all 64
        // partials, one barrier, gather both halves. write red[vidx][tid]:
        // consecutive-tid, conflict-free. read stride 16, RPAD%32==8 ->
        // 2-way = free.
        #pragma unroll
        for (int bi = 0; bi < 4; ++bi)
            #pragma unroll
            for (int j = 0; j < 8; ++j) {
                red0[(size_t)(bi * 8 + j) * RPAD + tid] = acc[bi][j];
                red1[(size_t)(bi * 8 + j) * RPAD + tid] = acc[4 + bi][j];
            }
        __syncthreads();                   // W
        {
            const float* rp0 = red0 + (size_t)(rb_ * 8 + rj) * RPAD + rtt;
            const float* rp1 = red1 + (size_t)(rb_ * 8 + rj) * RPAD + rtt;
            float a0 = 0.f, a1 = 0.f, a2 = 0.f, a3 = 0.f;
            float c0 = 0.f, c1 = 0.f, c2 = 0.f, c3 = 0.f;
            #pragma unroll
            for (int k2 = 0; k2 < 32; k2 += 4) {
                a0 += rp0[(k2 + 0) * 16];
                a1 += rp0[(k2 + 1) * 16];
                a2 += rp0[(k2 + 2) * 16];
                a3 += rp0[(k2 + 3) * 16];
                c0 += rp1[(k2 + 0) * 16];
                c1 += rp1[(k2 + 1) * 16];
                c2 += rp1[(k2 + 2) * 16];
                c3 += rp1[(k2 + 3) * 16];
            }
            gsum[rb_ * 128 + rgc]       = (a0 + a1) + (a2 + a3);
            gsum[(4 + rb_) * 128 + rgc] = (c0 + c1) + (c2 + c3);
        }
        __syncthreads();                   // G: gsum complete

        // ---- cell update + SPLIT PUBLISH: each cell wave drains its own
        // stores then sets its own flag. Non-cell waves are already racing
        // into t+1's poll+stage (no end barrier).
        if (cell_act) {
            float ii = hsig(gi + gsum[cb * 128 + chc]);
            float ff = hsig(gf + gsum[cb * 128 + 32 + chc]);
            float gv = htanh(gg + gsum[cb * 128 + 64 + chc]);
            float oo = hsig(go + gsum[cb * 128 + 96 + chc]);
            creg = ff * creg + ii * gv;
            __hip_atomic_store(out + (size_t)t * BH + cell_h, oo * htanh(creg),
                               __ATOMIC_RELAXED, __HIP_MEMORY_SCOPE_AGENT);
            asm volatile("s_waitcnt vmcnt(0)" ::: "memory");
            if ((tid & 63) == 0)
                __hip_atomic_store(myflag, (unsigned)(t + 1), __ATOMIC_RELAXED,
                                   __HIP_MEMORY_SCOPE_AGENT);
        }
        // no end barrier: next iteration's S barrier re-synchronizes.
    }
}

// ---------------------------------------------------------------------------
extern "C" void kernel_launch(void* const* d_in, const int* in_sizes, int n_in,
                              void* d_out, int out_size, void* d_ws, size_t ws_size,
                              hipStream_t stream) {
    const float* x  = (const float*)d_in[0];   // [T,B,D]
    const float* Wx = (const float*)d_in[1];   // [D,4H]
    const float* Wh = (const float*)d_in[2];   // [H,4H]
    const float* bs = (const float*)d_in[3];   // [4H]
    float* out = (float*)d_out;                // [T,B,H] — doubles as h history

    // ws layout (floats): Gx 33,554,432 | per-wave flags (1024 u32)
    float* Gx = (float*)d_ws;
    unsigned* flags = (unsigned*)(Gx + (size_t)MM * G4);

    zero_bar<<<dim3(1), dim3(1024), 0, stream>>>(flags);

    // Gx = X @ Wx + b for all timesteps at once
    gx_gemm<<<dim3(G4 / 128, MM / 128), dim3(256), 0, stream>>>(x, Wx, bs, Gx);

    // all 128 recurrent steps in one plain-launch persistent kernel
    lstm_persist<<<dim3(NWG), dim3(512), 0, stream>>>(Gx, Wh, out, flags);
}